// Round 1
// baseline (455.353 us; speedup 1.0000x reference)
//
#include <hip/hip_runtime.h>
#include <math.h>

typedef unsigned short u16;
typedef __attribute__((ext_vector_type(8))) short bf16x8;
typedef __attribute__((ext_vector_type(4))) float f32x4;
typedef __attribute__((ext_vector_type(4))) int i32x4;
typedef __attribute__((ext_vector_type(4))) short s16x4;
typedef __attribute__((ext_vector_type(4))) unsigned short u16x4;

#define MFMA16(a,b,c) __builtin_amdgcn_mfma_f32_16x16x32_bf16((a),(b),(c),0,0,0)

__device__ __forceinline__ u16 f2bf(float x){
  unsigned int u = __float_as_uint(x);
  u += 0x7fffu + ((u >> 16) & 1u);   // RNE
  return (u16)(u >> 16);
}
__device__ __forceinline__ float bf2f(u16 x){
  return __uint_as_float(((unsigned)x) << 16);
}
// async global->LDS, 16B per lane. LDS image must be lane-linear.
__device__ __forceinline__ void gload16(const void* g, void* l){
  __builtin_amdgcn_global_load_lds((const __attribute__((address_space(1))) void*)g,
                                   (__attribute__((address_space(3))) void*)l, 16, 0, 0);
}

// ---------------------------------------------------------------------------
// prep: fp32->bf16 + weight transposes + maskP packing.
// maskP[b][rt(16)][col(1024)][p(16)] bf16, p = row-in-16 (MFMA C-layout order).
// grid = 4096 x 256.
// ---------------------------------------------------------------------------
__global__ __launch_bounds__(256) void prep(
    const float* __restrict__ nodes, const float* __restrict__ q1, const float* __restrict__ lastn,
    const float* __restrict__ mask,
    const float* __restrict__ Wqf, const float* __restrict__ Wql, const float* __restrict__ Wk,
    const float* __restrict__ Wv, const float* __restrict__ Wc,
    u16* __restrict__ nodesb, u16* __restrict__ q1b, u16* __restrict__ lastb,
    u16* __restrict__ WtKV, u16* __restrict__ WtQF, u16* __restrict__ WtQL, u16* __restrict__ WtC,
    u16* __restrict__ maskP)
{
  const int tid = blockIdx.x * 256 + threadIdx.x;
  const int NT = 1048576;
  for (int i = tid; i < 4194304; i += NT) {
    float4 v = ((const float4*)nodes)[i];
    u16x4 o; o[0]=f2bf(v.x); o[1]=f2bf(v.y); o[2]=f2bf(v.z); o[3]=f2bf(v.w);
    *(u16x4*)&nodesb[i*4] = o;
  }
  {
    float4 v = ((const float4*)q1)[tid];
    u16x4 o; o[0]=f2bf(v.x); o[1]=f2bf(v.y); o[2]=f2bf(v.z); o[3]=f2bf(v.w);
    *(u16x4*)&q1b[tid*4] = o;
    v = ((const float4*)lastn)[tid];
    o[0]=f2bf(v.x); o[1]=f2bf(v.y); o[2]=f2bf(v.z); o[3]=f2bf(v.w);
    *(u16x4*)&lastb[tid*4] = o;
  }
  if (tid < 262144) {
    int n = tid >> 9, k = tid & 511;
    WtQF[tid] = f2bf(Wqf[k*512 + n]);
    WtQL[tid] = f2bf(Wql[k*512 + n]);
    WtC[tid]  = f2bf(Wc[k*512 + n]);
  }
  if (tid < 524288) {
    int n = tid >> 9, k = tid & 511;
    WtKV[tid] = f2bf(n < 512 ? Wk[k*512 + n] : Wv[k*512 + (n-512)]);
  }
  if (tid < 524288) {  // maskP: tid = (b*16 + rt)*1024 + c
    int brt = tid >> 10, c = tid & 1023;
    const float* mp = mask + (brt*16)*1024 + c;
    u16 vals[16];
    #pragma unroll
    for (int p=0;p<16;p++) vals[p] = f2bf(mp[p*1024]);
    *(i32x4*)&maskP[tid*16]     = *(i32x4*)&vals[0];
    *(i32x4*)&maskP[tid*16 + 8] = *(i32x4*)&vals[8];
  }
}

// ---------------------------------------------------------------------------
// kvq: merged K|V projection GEMM + Q projection GEMM in one dispatch.
//
// bids 0..1023   : Q tiles (64x64, BK=64). Q = (q1@Wqf + last@Wql)/sqrt(32).
// bids 1024..3071: K|V tiles (128x128, BK=32, dbuf). The independent q-blocks
//                  fill the kv-blocks' barrier-drain latency bubbles.
//
// LDS = 32768 B exactly -> 5 blocks/CU (was 35840 -> 4/CU). The kv epilogue
// transpose is therefore split into two 64-col passes through a 64x140
// buffer that reuses the staging region.
// ---------------------------------------------------------------------------
__global__ __launch_bounds__(256) void kvq(
    const u16* __restrict__ A, const u16* __restrict__ Bw,
    u16* __restrict__ Kout, u16* __restrict__ Vout,
    const u16* __restrict__ A1, const u16* __restrict__ A2,
    const u16* __restrict__ B1, const u16* __restrict__ B2,
    u16* __restrict__ Qout)
{
  __shared__ u16 smem[16384];   // 32768 B
  const int t = threadIdx.x, w = t >> 6, l = t & 63, q = l >> 4, ln = l & 15;

  if (blockIdx.x < 1024) {
    // ======================= gemm_q branch ==================================
    const int bidq = blockIdx.x;
    const int mb = (bidq >> 6)*8 + (bidq & 7);
    const int nb = (bidq >> 3) & 7;
    const int wm = (w >> 1) * 32, wn = (w & 1) * 32;
    u16* As = smem;            // [koct(8)][row(64)][8]
    u16* Bs = smem + 4096;
    f32x4 acc[2][2];
    #pragma unroll
    for (int i=0;i<2;i++)
      #pragma unroll
      for (int j=0;j<2;j++)
        #pragma unroll
        for (int r=0;r<4;r++) acc[i][j][r] = 0.f;
    const int m0 = mb*64, n0 = nb*64;
    for (int kc = 0; kc < 16; kc++) {
      const u16* Ap = (kc < 8) ? A1 : A2;
      const u16* Bp = (kc < 8) ? B1 : B2;
      const int k0 = (kc & 7) * 64;
      __syncthreads();
      #pragma unroll
      for (int c=0;c<2;c++) {
        int chunk = t + 256*c;
        int row = chunk & 63, ko = chunk >> 6;
        gload16(&Ap[(m0+row)*512 + k0 + ko*8], &As[chunk*8]);
        gload16(&Bp[(n0+row)*512 + k0 + ko*8], &Bs[chunk*8]);
      }
      __syncthreads();
      #pragma unroll
      for (int ko=0;ko<2;ko++) {
        bf16x8 af[2], bfr[2];
        #pragma unroll
        for (int i=0;i<2;i++) af[i] = *(bf16x8*)&As[((ko*4+q)*64 + wm + i*16 + ln)*8];
        #pragma unroll
        for (int j=0;j<2;j++) bfr[j] = *(bf16x8*)&Bs[((ko*4+q)*64 + wn + j*16 + ln)*8];
        #pragma unroll
        for (int i=0;i<2;i++)
          #pragma unroll
          for (int j=0;j<2;j++)
            acc[i][j] = MFMA16(af[i], bfr[j], acc[i][j]);
      }
    }
    const float sc = 0.17677669529663687f;
    #pragma unroll
    for (int i=0;i<2;i++) {
      int gm = m0 + wm + i*16 + q*4;
      int bb = gm >> 8, pm = gm & 255;
      #pragma unroll
      for (int j=0;j<2;j++) {
        int gn = n0 + wn + j*16 + ln;
        int h = gn >> 5, d = gn & 31;
        u16* qp = Qout + ((bb*16 + h)*256 + pm)*32 + d;
        #pragma unroll
        for (int r=0;r<4;r++) qp[r*32] = f2bf(acc[i][j][r]*sc);
      }
    }
    return;
  }

  // ========================= gemm_kv branch =================================
  const int bid = blockIdx.x - 1024;
  const int mb = (bid >> 6)*8 + (bid & 7);
  const int nb = (bid >> 3) & 7;
  const int wm = (w >> 1) * 64, wn = (w & 1) * 64;
  f32x4 acc[4][4];
  #pragma unroll
  for (int i=0;i<4;i++)
    #pragma unroll
    for (int j=0;j<4;j++)
      #pragma unroll
      for (int r=0;r<4;r++) acc[i][j][r] = 0.f;
  const int m0 = mb*128, n0 = nb*128;

  #define STAGE_KV(kc_, b_) { \
    u16* sa = smem + (b_)*8192; \
    u16* sb = sa + 4096; \
    _Pragma("unroll") \
    for (int c=0;c<2;c++){ \
      int chunk = c*256 + t; \
      int ko = chunk >> 7, r_ = chunk & 127; \
      gload16(&A[(m0+r_)*512 + (kc_)*32 + ko*8], &sa[chunk*8]); \
      gload16(&Bw[(n0+r_)*512 + (kc_)*32 + ko*8], &sb[chunk*8]); \
    } }

  STAGE_KV(0, 0);
  for (int kc = 0; kc < 16; kc++) {
    __syncthreads();
    if (kc < 15) STAGE_KV(kc+1, (kc+1)&1);
    const u16* sa = smem + (kc&1)*8192;
    const u16* sb = sa + 4096;
    bf16x8 af[4], bfr[4];
    #pragma unroll
    for (int i=0;i<4;i++) af[i] = *(bf16x8*)&sa[(q*128 + wm + i*16 + ln)*8];
    #pragma unroll
    for (int j=0;j<4;j++) bfr[j] = *(bf16x8*)&sb[(q*128 + wn + j*16 + ln)*8];
    #pragma unroll
    for (int i=0;i<4;i++)
      #pragma unroll
      for (int j=0;j<4;j++)
        acc[i][j] = MFMA16(af[i], bfr[j], acc[i][j]);
  }
  #undef STAGE_KV

  // ---- epilogue: two 64-col half-passes through a 64x140 transpose buffer.
  //      Pass h: waves with (w&1)==h own cols h*64..h*64+63 and write their
  //      4x4 fragments; then all 4 waves read/store those 64 cols. ----
  const int bb_ = mb >> 3, mloc = (mb & 7)*128;
  #pragma unroll
  for (int h = 0; h < 2; ++h) {
    __syncthreads();
    if ((w & 1) == h) {
      #pragma unroll
      for (int i=0;i<4;i++) {
        #pragma unroll
        for (int j=0;j<4;j++) {
          s16x4 o;
          #pragma unroll
          for (int r=0;r<4;r++) o[r] = (short)f2bf(acc[i][j][r]);
          *(s16x4*)&smem[(j*16 + ln)*140 + wm + i*16 + q*4] = o;
        }
      }
    }
    __syncthreads();
    const int hh = h*2 + (w >> 1);          // head within this nb-group
    if (nb < 4) {
      u16* base = Kout + ((bb_*16 + nb*4 + hh)*1024 + mloc)*32;
      #pragma unroll
      for (int it=0; it<4; it++) {
        int idx = (w&1)*2048 + it*512 + l*8;
        int m_ = idx >> 5, d0 = idx & 31;
        int cl = (w >> 1)*32 + d0;          // local col in buffer
        u16 v[8];
        #pragma unroll
        for (int dd=0;dd<8;dd++) v[dd] = smem[(cl+dd)*140 + m_];
        *(i32x4*)&base[m_*32 + d0] = *(i32x4*)&v[0];
      }
    } else {
      u16* base = Vout + ((bb_*16 + (nb-4)*4 + hh)*32)*1024 + mloc;
      #pragma unroll
      for (int it=0; it<4; it++) {
        int dloc = (w&1)*16 + it*4 + (l >> 4);   // 0..31 across the 2 waves
        int mc_ = (l & 15)*8;
        *(i32x4*)&base[dloc*1024 + mc_] = *(i32x4*)&smem[((w>>1)*32 + dloc)*140 + mc_];
      }
    }
  }
}

// ---------------------------------------------------------------------------
// Fused attention per (b, h, pomo64). grid = 2048, 4 waves.
// XCD swizzle: bid = bhhi*32 + pt*8 + bhlo -> 4 pt-blocks sharing K/V on one
// XCD within a 32-bid window.
// ---------------------------------------------------------------------------
__global__ __launch_bounds__(256) void attn(const u16* __restrict__ Qg, const u16* __restrict__ Kg,
                                            const u16* __restrict__ Vtg, const u16* __restrict__ maskP,
                                            u16* __restrict__ Og)
{
  const int bid = blockIdx.x;
  const int bh = (bid >> 5)*8 + (bid & 7);       // 0..511
  const int pt = (bid >> 3) & 3;
  const int h = bh & 15, bb = bh >> 4;
  const int t = threadIdx.x, w = t >> 6, l = t & 63, q = l >> 4, ln = l & 15;
  __shared__ u16 Qs[2048];     // [qk(4)][row(64)][8]
  __shared__ u16 Ks[4096];     // [qk(4)][m(128)][8]
  __shared__ u16 Vs[4096];     // [moct(16)][d(32)][8]
  __shared__ u16 Ps[4*640];    // per wave [16][40]
  u16* Pw = &Ps[w*640];
  const int qbase = ((bb*16 + h)*256 + pt*64)*32;
  gload16(&Qg[qbase + (t & 63)*32 + (t >> 6)*8], &Qs[t*8]);
  const int kbase = (bb*16 + h)*1024*32;
  const int vbase = (bb*16 + h)*32*1024;
  float rs[4] = {0.f,0.f,0.f,0.f};
  f32x4 oacc[2];
  #pragma unroll
  for (int dt=0;dt<2;dt++)
    #pragma unroll
    for (int r=0;r<4;r++) oacc[dt][r] = 0.f;
  __syncthreads();
  const bf16x8 aq = *(bf16x8*)&Qs[(q*64 + w*16 + ln)*8];
  const u16* mrow = maskP + (bb*16 + pt*4 + w)*16384 + q*4;
  for (int mc = 0; mc < 8; mc++) {
    __syncthreads();
    gload16(&Kg[kbase + (mc*128 + (t & 127))*32 + (t >> 7)*8],       &Ks[t*8]);
    gload16(&Kg[kbase + (mc*128 + (t & 127))*32 + ((t >> 7)+2)*8],   &Ks[(t+256)*8]);
    gload16(&Vtg[vbase + (t & 31)*1024 + mc*128 + (t >> 5)*8],       &Vs[t*8]);
    gload16(&Vtg[vbase + (t & 31)*1024 + mc*128 + ((t >> 5)+8)*8],   &Vs[(t+256)*8]);
    u16x4 mq[8];
    #pragma unroll
    for (int j2=0;j2<8;j2++)
      mq[j2] = *(const u16x4*)&mrow[(mc*128 + j2*16 + ln)*16];
    __syncthreads();
    #pragma unroll
    for (int ch=0; ch<4; ch++) {
      bf16x8 bk0 = *(bf16x8*)&Ks[(q*128 + (ch*2+0)*16 + ln)*8];
      bf16x8 bk1 = *(bf16x8*)&Ks[(q*128 + (ch*2+1)*16 + ln)*8];
      f32x4 zz = {0.f,0.f,0.f,0.f};
      f32x4 s0 = MFMA16(aq, bk0, zz);
      f32x4 s1 = MFMA16(aq, bk1, zz);
      #pragma unroll
      for (int r=0;r<4;r++) {
        float e0 = __expf(s0[r] + bf2f(mq[ch*2+0][r]));
        float e1 = __expf(s1[r] + bf2f(mq[ch*2+1][r]));
        rs[r] += e0 + e1;
        Pw[(q*4+r)*40 + ln]      = f2bf(e0);
        Pw[(q*4+r)*40 + 16 + ln] = f2bf(e1);
      }
      bf16x8 ap  = *(bf16x8*)&Pw[ln*40 + q*8];
      bf16x8 bv0 = *(bf16x8*)&Vs[((ch*4+q)*32 + ln)*8];
      bf16x8 bv1 = *(bf16x8*)&Vs[((ch*4+q)*32 + 16 + ln)*8];
      oacc[0] = MFMA16(ap, bv0, oacc[0]);
      oacc[1] = MFMA16(ap, bv1, oacc[1]);
    }
  }
  #pragma unroll
  for (int r=0;r<4;r++) {
    float v = rs[r];
    v += __shfl_xor(v,1); v += __shfl_xor(v,2); v += __shfl_xor(v,4); v += __shfl_xor(v,8);
    rs[r] = __builtin_amdgcn_rcpf(v);
  }
  const int orow = bb*256 + pt*64 + w*16 + q*4;
  #pragma unroll
  for (int dt=0;dt<2;dt++)
    #pragma unroll
    for (int r=0;r<4;r++)
      Og[(orow + r)*512 + h*32 + dt*16 + ln] = f2bf(oacc[dt][r]*rs[r]);
}

// ---------------------------------------------------------------------------
// cmbfin: fused combine-GEMM + pointer-GEMM + tanh-softmax.
// 1024 threads (16 waves), 32 rows x 1024 cols per block, grid = 256
// (1 block/CU). XCD swizzle: bid = rg*32 + bb -> all 8 row-groups of batch b
// on one XCD (nodesb[b] = 1 MB stays in that XCD's L2; 4 b's = 4 MB = L2).
// ---------------------------------------------------------------------------
__global__ __launch_bounds__(1024) void cmbfin(const u16* __restrict__ oc, const u16* __restrict__ WtC,
                                               const float* __restrict__ bias,
                                               const u16* __restrict__ nodesb, const u16* __restrict__ maskP,
                                               float* __restrict__ out)
{
  const int bid = blockIdx.x;
  const int bb = bid & 31, rg = bid >> 5;     // rg 0..7: 32-row group
  const int t = threadIdx.x, w = t >> 6, l = t & 63, q = l >> 4, ln = l & 15;
  __shared__ u16 As[16384];     // oc tile [koct(64)][row(32)][8]
  __shared__ u16 Ms[16384];     // mh tile, same layout (k = combine out col)
  __shared__ float rsL[16][32];
  const int abase = (bb*256 + rg*32)*512;
  #pragma unroll
  for (int c=0;c<2;c++) {
    int chunk = t + 1024*c;
    gload16(&oc[abase + (chunk & 31)*512 + (chunk >> 5)*8], &As[chunk*8]);
  }
  __syncthreads();
  // ---- phase 1: combine. wave w covers cols w*32..w*32+31 ----
  f32x4 acc1[2][2];
  #pragma unroll
  for (int i=0;i<2;i++)
    #pragma unroll
    for (int ct=0;ct<2;ct++)
      #pragma unroll
      for (int r=0;r<4;r++) acc1[i][ct][r] = 0.f;
  for (int kc=0;kc<16;kc++) {
    bf16x8 af[2];
    #pragma unroll
    for (int i=0;i<2;i++) af[i] = *(bf16x8*)&As[((kc*4 + q)*32 + i*16 + ln)*8];
    #pragma unroll
    for (int ct=0;ct<2;ct++) {
      int col = w*32 + ct*16 + ln;
      bf16x8 bfr = *(const bf16x8*)&WtC[col*512 + kc*32 + q*8];
      #pragma unroll
      for (int i=0;i<2;i++) acc1[i][ct] = MFMA16(af[i], bfr, acc1[i][ct]);
    }
  }
  #pragma unroll
  for (int ct=0;ct<2;ct++) {
    int gn = w*32 + ct*16 + ln;
    float bv = bias[gn];
    #pragma unroll
    for (int i=0;i<2;i++)
      #pragma unroll
      for (int r=0;r<4;r++)
        Ms[(gn >> 3)*256 + (i*16 + q*4 + r)*8 + (gn & 7)] = f2bf(acc1[i][ct][r] + bv);
  }
  __syncthreads();
  // ---- phase 2: pointer logits + softmax. wave w covers cols w*64.. ----
  float rloc[2][4] = {{0.f,0.f,0.f,0.f},{0.f,0.f,0.f,0.f}};
  const int nbase = bb*524288;
  f32x4 acc[2][4];
  #pragma unroll
  for (int i=0;i<2;i++)
    #pragma unroll
    for (int ct=0;ct<4;ct++)
      #pragma unroll
      for (int r=0;r<4;r++) acc[i][ct][r] = 0.f;
  for (int kc=0;kc<16;kc++) {
    bf16x8 af[2];
    #pragma unroll
    for (int i=0;i<2;i++) af[i] = *(bf16x8*)&Ms[((kc*4 + q)*32 + i*16 + ln)*8];
    #pragma unroll
    for (int ct=0;ct<4;ct++) {
      int col = w*64 + ct*16 + ln;
      bf16x8 bfr = *(const bf16x8*)&nodesb[nbase + col*512 + kc*32 + q*8];
      #pragma unroll
      for (int i=0;i<2;i++) acc[i][ct] = MFMA16(af[i], bfr, acc[i][ct]);
    }
  }
  const float c2 = 0.08838834764831843f;   // 2/sqrt(512)
  const int prow_base = bb*256 + rg*32;
  #pragma unroll
  for (int i=0;i<2;i++) {
    #pragma unroll
    for (int ct=0;ct<4;ct++) {
      int col0 = w*64 + ct*16 + ln;
      u16x4 mv = *(const u16x4*)&maskP[((bb*16 + rg*2 + i)*1024 + col0)*16 + q*4];
      #pragma unroll
      for (int r=0;r<4;r++) {
        float x = acc[i][ct][r] * c2;
        x = fminf(fmaxf(x, -30.f), 30.f);
        float e2 = __expf(x);
        float lg = 10.f*(e2 - 1.f)*__builtin_amdgcn_rcpf(e2 + 1.f) + bf2f(mv[r]);
        float e = __expf(lg);
        rloc[i][r] += e;
        acc[i][ct][r] = e;
      }
    }
  }
  #pragma unroll
  for (int i=0;i<2;i++)
    #pragma unroll
    for (int r=0;r<4;r++) {
      float v = rloc[i][r];
      v += __shfl_xor(v,1); v += __shfl_xor(v,2); v += __shfl_xor(v,4); v += __shfl_xor(v,8);
      rloc[i][r] = v;
    }
  if (ln == 0) {
    #pragma unroll
    for (int i=0;i<2;i++)
      #pragma unroll
      for (int r=0;r<4;r++) rsL[w][i*16 + q*4 + r] = rloc[i][r];
  }
  __syncthreads();
  float inv[2][4];
  #pragma unroll
  for (int i=0;i<2;i++)
    #pragma unroll
    for (int r=0;r<4;r++) {
      float tot = 0.f;
      #pragma unroll
      for (int ww=0;ww<16;ww++) tot += rsL[ww][i*16 + q*4 + r];
      inv[i][r] = __builtin_amdgcn_rcpf(tot);
    }
  #pragma unroll
  for (int i=0;i<2;i++)
    #pragma unroll
    for (int ct=0;ct<4;ct++) {
      int col0 = w*64 + ct*16 + ln;
      #pragma unroll
      for (int r=0;r<4;r++)
        out[(prow_base + i*16 + q*4 + r)*1024 + col0] = acc[i][ct][r]*inv[i][r];
    }
}

extern "C" void kernel_launch(void* const* d_in, const int* in_sizes, int n_in,
                              void* d_out, int out_size, void* d_ws, size_t ws_size,
                              hipStream_t stream)
{
  (void)in_sizes; (void)n_in; (void)out_size; (void)ws_size;
  const float* nodes = (const float*)d_in[0];
  const float* q1    = (const float*)d_in[1];
  const float* lastn = (const float*)d_in[2];
  const float* mask  = (const float*)d_in[3];
  const float* Wqf   = (const float*)d_in[4];
  const float* Wql   = (const float*)d_in[5];
  const float* Wk    = (const float*)d_in[6];
  const float* Wv    = (const float*)d_in[7];
  const float* Wc    = (const float*)d_in[8];
  const float* bias  = (const float*)d_in[9];
  float* out = (float*)d_out;

  char* p = (char*)d_ws;
  u16* nodesb = (u16*)p; p += 33554432;   // [32][1024][512] bf16
  u16* q1b    = (u16*)p; p += 8388608;    // [32][256][512]
  u16* lastb  = (u16*)p; p += 8388608;
  u16* WtKV   = (u16*)p; p += 1048576;    // [1024][512]
  u16* WtQF   = (u16*)p; p += 524288;
  u16* WtQL   = (u16*)p; p += 524288;
  u16* WtC    = (u16*)p; p += 524288;
  u16* Kt     = (u16*)p; p += 33554432;   // K [32][16][1024][32]
  u16* Vt     = (u16*)p; p += 33554432;   // V^T [32][16][32][1024]
  u16* Qh     = (u16*)p; p += 8388608;    // Q(scaled) [32][16][256][32]
  u16* maskP  = (u16*)p; p += 16777216;   // [32][16][1024][16] bf16
  u16* oc  = lastb;   // dead after kvq (q-branch reads lastb; attn runs later)

  prep<<<4096, 256, 0, stream>>>(nodes, q1, lastn, mask, Wqf, Wql, Wk, Wv, Wc,
                                 nodesb, q1b, lastb, WtKV, WtQF, WtQL, WtC, maskP);
  kvq<<<3072, 256, 0, stream>>>(nodesb, WtKV, Kt, Vt, q1b, lastb, WtQF, WtQL, Qh);
  attn<<<2048, 256, 0, stream>>>(Qh, Kt, Vt, maskP, oc);
  cmbfin<<<256, 1024, 0, stream>>>(oc, WtC, bias, nodesb, maskP, out);
}

// Round 2
// 383.051 us; speedup vs baseline: 1.1888x; 1.1888x over previous
//
#include <hip/hip_runtime.h>
#include <math.h>

typedef unsigned short u16;
typedef __attribute__((ext_vector_type(8))) short bf16x8;
typedef __attribute__((ext_vector_type(4))) float f32x4;
typedef __attribute__((ext_vector_type(4))) int i32x4;
typedef __attribute__((ext_vector_type(4))) short s16x4;
typedef __attribute__((ext_vector_type(4))) unsigned short u16x4;

#define MFMA16(a,b,c) __builtin_amdgcn_mfma_f32_16x16x32_bf16((a),(b),(c),0,0,0)

__device__ __forceinline__ u16 f2bf(float x){
  unsigned int u = __float_as_uint(x);
  u += 0x7fffu + ((u >> 16) & 1u);   // RNE
  return (u16)(u >> 16);
}
__device__ __forceinline__ float bf2f(u16 x){
  return __uint_as_float(((unsigned)x) << 16);
}
// async global->LDS, 16B per lane. LDS image must be lane-linear.
__device__ __forceinline__ void gload16(const void* g, void* l){
  __builtin_amdgcn_global_load_lds((const __attribute__((address_space(1))) void*)g,
                                   (__attribute__((address_space(3))) void*)l, 16, 0, 0);
}

// ---------------------------------------------------------------------------
// prep: fp32->bf16 + weight transposes + maskP packing.
// qlb[8192][1024] = [q1 | last]  (concat along K so Q-proj is one K=1024 GEMM)
// WtQ2[512][1024] = [Wqf | Wql]  (B^T layout, concat along K)
// maskP[b][rt(16)][col(1024)][p(16)] bf16, p = row-in-16 (MFMA C-layout order).
// grid = 4096 x 256.
// ---------------------------------------------------------------------------
__global__ __launch_bounds__(256) void prep(
    const float* __restrict__ nodes, const float* __restrict__ q1, const float* __restrict__ lastn,
    const float* __restrict__ mask,
    const float* __restrict__ Wqf, const float* __restrict__ Wql, const float* __restrict__ Wk,
    const float* __restrict__ Wv, const float* __restrict__ Wc,
    u16* __restrict__ nodesb, u16* __restrict__ qlb,
    u16* __restrict__ WtKV, u16* __restrict__ WtQ2, u16* __restrict__ WtC,
    u16* __restrict__ maskP)
{
  const int tid = blockIdx.x * 256 + threadIdx.x;
  const int NT = 1048576;
  for (int i = tid; i < 4194304; i += NT) {
    float4 v = ((const float4*)nodes)[i];
    u16x4 o; o[0]=f2bf(v.x); o[1]=f2bf(v.y); o[2]=f2bf(v.z); o[3]=f2bf(v.w);
    *(u16x4*)&nodesb[i*4] = o;
  }
  {
    const int m = tid >> 7, k4 = (tid & 127)*4;
    float4 v = ((const float4*)q1)[tid];
    u16x4 o; o[0]=f2bf(v.x); o[1]=f2bf(v.y); o[2]=f2bf(v.z); o[3]=f2bf(v.w);
    *(u16x4*)&qlb[m*1024 + k4] = o;
    v = ((const float4*)lastn)[tid];
    o[0]=f2bf(v.x); o[1]=f2bf(v.y); o[2]=f2bf(v.z); o[3]=f2bf(v.w);
    *(u16x4*)&qlb[m*1024 + 512 + k4] = o;
  }
  if (tid < 262144) {
    int n = tid >> 9, k = tid & 511;
    WtQ2[n*1024 + k]       = f2bf(Wqf[k*512 + n]);
    WtQ2[n*1024 + 512 + k] = f2bf(Wql[k*512 + n]);
    WtC[tid]  = f2bf(Wc[k*512 + n]);
  }
  if (tid < 524288) {
    int n = tid >> 9, k = tid & 511;
    WtKV[tid] = f2bf(n < 512 ? Wk[k*512 + n] : Wv[k*512 + (n-512)]);
  }
  if (tid < 524288) {  // maskP: tid = (b*16 + rt)*1024 + c
    int brt = tid >> 10, c = tid & 1023;
    const float* mp = mask + (brt*16)*1024 + c;
    u16 vals[16];
    #pragma unroll
    for (int p=0;p<16;p++) vals[p] = f2bf(mp[p*1024]);
    *(i32x4*)&maskP[tid*16]     = *(i32x4*)&vals[0];
    *(i32x4*)&maskP[tid*16 + 8] = *(i32x4*)&vals[8];
  }
}

// ---------------------------------------------------------------------------
// kvq: ONE code path, 8 waves (512 thr), 128x128 tile, BK=32 dbuf.
//   bids 0..255    : Q tiles  (A=qlb  [8192][1024], B=WtQ2 [512][1024], 32 kc)
//   bids 256..2303 : KV tiles (A=nodesb [32768][512], B=WtKV [1024][512], 16 kc)
// Per wave: 64x32 output -> acc[4][2] = 32 VGPR. __launch_bounds__(512,8)
// forces <=64 VGPR -> 8 waves/SIMD; LDS = 32768 exactly -> 4 blocks/CU
// (32 waves resident, 2x baseline). Epilogue: two 64-col passes through a
// 64x140 transpose buffer (reuses staging LDS).
// ---------------------------------------------------------------------------
__global__ __launch_bounds__(512, 8) void kvq(
    const u16* __restrict__ Akv, const u16* __restrict__ Bkv,
    const u16* __restrict__ Aq,  const u16* __restrict__ Bq,
    u16* __restrict__ Kout, u16* __restrict__ Vout, u16* __restrict__ Qout)
{
  __shared__ u16 smem[16384];   // 32768 B: 2 x (A 4096 + B 4096)
  const int t = threadIdx.x, w = t >> 6, l = t & 63, q = l >> 4, ln = l & 15;
  const int wc = w & 3;
  const int wm = (w >> 2) * 64, wn = wc * 32;

  const bool isq = blockIdx.x < 256;
  int mb, nb, ksteps, kstr;
  const u16 *Ab, *Bb;
  if (isq) {
    const int bid = blockIdx.x;
    mb = bid >> 2; nb = bid & 3;
    ksteps = 32; kstr = 1024; Ab = Aq; Bb = Bq;
  } else {
    const int bid = blockIdx.x - 256;
    mb = (bid >> 6)*8 + (bid & 7);        // XCD swizzle (same-A blocks share XCD)
    nb = (bid >> 3) & 7;
    ksteps = 16; kstr = 512; Ab = Akv; Bb = Bkv;
  }
  const int m0 = mb*128, n0 = nb*128;

  f32x4 acc[4][2];
  #pragma unroll
  for (int i=0;i<4;i++)
    #pragma unroll
    for (int j=0;j<2;j++)
      #pragma unroll
      for (int r=0;r<4;r++) acc[i][j][r] = 0.f;

  // staging: 512 threads x 16B = one full 128x32 tile per array per step
  const int r_ = t & 127, ko = t >> 7;
  const u16* Aaddr = Ab + (m0 + r_)*kstr + ko*8;
  const u16* Baddr = Bb + (n0 + r_)*kstr + ko*8;

  #define STAGE(kc_, b_) { \
    u16* s = smem + (b_)*8192; \
    gload16(Aaddr + (kc_)*32, &s[t*8]); \
    gload16(Baddr + (kc_)*32, &s[4096 + t*8]); }

  STAGE(0, 0);
  #pragma unroll 2
  for (int kc = 0; kc < ksteps; kc++) {
    __syncthreads();
    if (kc + 1 < ksteps) STAGE(kc+1, (kc+1)&1);
    const u16* sa = smem + (kc&1)*8192;
    const u16* sb = sa + 4096;
    bf16x8 bfr[2];
    #pragma unroll
    for (int j=0;j<2;j++) bfr[j] = *(bf16x8*)&sb[(q*128 + wn + j*16 + ln)*8];
    #pragma unroll
    for (int i=0;i<4;i++) {
      bf16x8 af = *(bf16x8*)&sa[(q*128 + wm + i*16 + ln)*8];
      #pragma unroll
      for (int j=0;j<2;j++)
        acc[i][j] = MFMA16(af, bfr[j], acc[i][j]);
    }
  }
  #undef STAGE

  // ---- epilogue: two 64-col passes via 64x140 buffer (17920 B) ----
  const float scale = isq ? 0.17677669529663687f : 1.0f;
  const int bb_ = mb >> 3, mloc = (mb & 7)*128;   // kv decode
  const int bbq = mb >> 1, pm0 = (mb & 1)*128;    // q  decode
  #pragma unroll
  for (int h = 0; h < 2; ++h) {
    __syncthreads();
    if ((wc >> 1) == h) {
      const int cl0 = (wc & 1)*32;
      #pragma unroll
      for (int i=0;i<4;i++)
        #pragma unroll
        for (int j=0;j<2;j++) {
          s16x4 o;
          #pragma unroll
          for (int r=0;r<4;r++) o[r] = (short)f2bf(acc[i][j][r]*scale);
          *(s16x4*)&smem[(cl0 + j*16 + ln)*140 + wm + i*16 + q*4] = o;
        }
    }
    __syncthreads();
    #pragma unroll
    for (int hc=0; hc<2; ++hc) {
      const int hh = h*2 + hc;
      if (isq) {
        const int m_ = t >> 2, d0 = (t & 3)*8;
        u16 v[8];
        #pragma unroll
        for (int dd=0;dd<8;dd++) v[dd] = smem[(hc*32 + d0 + dd)*140 + m_];
        *(i32x4*)&Qout[((bbq*16 + nb*4 + hh)*256 + pm0 + m_)*32 + d0] = *(i32x4*)&v[0];
      } else if (nb < 4) {
        const int m_ = t >> 2, d0 = (t & 3)*8;
        u16 v[8];
        #pragma unroll
        for (int dd=0;dd<8;dd++) v[dd] = smem[(hc*32 + d0 + dd)*140 + m_];
        *(i32x4*)&Kout[((bb_*16 + nb*4 + hh)*1024 + mloc + m_)*32 + d0] = *(i32x4*)&v[0];
      } else {
        const int d = t >> 4, mo = (t & 15)*8;
        *(i32x4*)&Vout[((bb_*16 + (nb-4)*4 + hh)*32 + d)*1024 + mloc + mo]
            = *(i32x4*)&smem[(hc*32 + d)*140 + mo];
      }
    }
  }
}

// ---------------------------------------------------------------------------
// Fused attention per (b, h, pomo64). grid = 2048, 4 waves.
// XCD swizzle: bid = bhhi*32 + pt*8 + bhlo -> 4 pt-blocks sharing K/V on one
// XCD within a 32-bid window.
// ---------------------------------------------------------------------------
__global__ __launch_bounds__(256) void attn(const u16* __restrict__ Qg, const u16* __restrict__ Kg,
                                            const u16* __restrict__ Vtg, const u16* __restrict__ maskP,
                                            u16* __restrict__ Og)
{
  const int bid = blockIdx.x;
  const int bh = (bid >> 5)*8 + (bid & 7);       // 0..511
  const int pt = (bid >> 3) & 3;
  const int h = bh & 15, bb = bh >> 4;
  const int t = threadIdx.x, w = t >> 6, l = t & 63, q = l >> 4, ln = l & 15;
  __shared__ u16 Qs[2048];     // [qk(4)][row(64)][8]
  __shared__ u16 Ks[4096];     // [qk(4)][m(128)][8]
  __shared__ u16 Vs[4096];     // [moct(16)][d(32)][8]
  __shared__ u16 Ps[4*640];    // per wave [16][40]
  u16* Pw = &Ps[w*640];
  const int qbase = ((bb*16 + h)*256 + pt*64)*32;
  gload16(&Qg[qbase + (t & 63)*32 + (t >> 6)*8], &Qs[t*8]);
  const int kbase = (bb*16 + h)*1024*32;
  const int vbase = (bb*16 + h)*32*1024;
  float rs[4] = {0.f,0.f,0.f,0.f};
  f32x4 oacc[2];
  #pragma unroll
  for (int dt=0;dt<2;dt++)
    #pragma unroll
    for (int r=0;r<4;r++) oacc[dt][r] = 0.f;
  __syncthreads();
  const bf16x8 aq = *(bf16x8*)&Qs[(q*64 + w*16 + ln)*8];
  const u16* mrow = maskP + (bb*16 + pt*4 + w)*16384 + q*4;
  for (int mc = 0; mc < 8; mc++) {
    __syncthreads();
    gload16(&Kg[kbase + (mc*128 + (t & 127))*32 + (t >> 7)*8],       &Ks[t*8]);
    gload16(&Kg[kbase + (mc*128 + (t & 127))*32 + ((t >> 7)+2)*8],   &Ks[(t+256)*8]);
    gload16(&Vtg[vbase + (t & 31)*1024 + mc*128 + (t >> 5)*8],       &Vs[t*8]);
    gload16(&Vtg[vbase + (t & 31)*1024 + mc*128 + ((t >> 5)+8)*8],   &Vs[(t+256)*8]);
    u16x4 mq[8];
    #pragma unroll
    for (int j2=0;j2<8;j2++)
      mq[j2] = *(const u16x4*)&mrow[(mc*128 + j2*16 + ln)*16];
    __syncthreads();
    #pragma unroll
    for (int ch=0; ch<4; ch++) {
      bf16x8 bk0 = *(bf16x8*)&Ks[(q*128 + (ch*2+0)*16 + ln)*8];
      bf16x8 bk1 = *(bf16x8*)&Ks[(q*128 + (ch*2+1)*16 + ln)*8];
      f32x4 zz = {0.f,0.f,0.f,0.f};
      f32x4 s0 = MFMA16(aq, bk0, zz);
      f32x4 s1 = MFMA16(aq, bk1, zz);
      #pragma unroll
      for (int r=0;r<4;r++) {
        float e0 = __expf(s0[r] + bf2f(mq[ch*2+0][r]));
        float e1 = __expf(s1[r] + bf2f(mq[ch*2+1][r]));
        rs[r] += e0 + e1;
        Pw[(q*4+r)*40 + ln]      = f2bf(e0);
        Pw[(q*4+r)*40 + 16 + ln] = f2bf(e1);
      }
      bf16x8 ap  = *(bf16x8*)&Pw[ln*40 + q*8];
      bf16x8 bv0 = *(bf16x8*)&Vs[((ch*4+q)*32 + ln)*8];
      bf16x8 bv1 = *(bf16x8*)&Vs[((ch*4+q)*32 + 16 + ln)*8];
      oacc[0] = MFMA16(ap, bv0, oacc[0]);
      oacc[1] = MFMA16(ap, bv1, oacc[1]);
    }
  }
  #pragma unroll
  for (int r=0;r<4;r++) {
    float v = rs[r];
    v += __shfl_xor(v,1); v += __shfl_xor(v,2); v += __shfl_xor(v,4); v += __shfl_xor(v,8);
    rs[r] = __builtin_amdgcn_rcpf(v);
  }
  const int orow = bb*256 + pt*64 + w*16 + q*4;
  #pragma unroll
  for (int dt=0;dt<2;dt++)
    #pragma unroll
    for (int r=0;r<4;r++)
      Og[(orow + r)*512 + h*32 + dt*16 + ln] = f2bf(oacc[dt][r]*rs[r]);
}

// ---------------------------------------------------------------------------
// cmbfin: fused combine-GEMM + pointer-GEMM + tanh-softmax.
// 1024 threads (16 waves), 32 rows x 1024 cols per block, grid = 256
// (1 block/CU). XCD swizzle: bid = rg*32 + bb -> all 8 row-groups of batch b
// on one XCD (nodesb[b] = 1 MB stays in that XCD's L2; 4 b's = 4 MB = L2).
// ---------------------------------------------------------------------------
__global__ __launch_bounds__(1024) void cmbfin(const u16* __restrict__ oc, const u16* __restrict__ WtC,
                                               const float* __restrict__ bias,
                                               const u16* __restrict__ nodesb, const u16* __restrict__ maskP,
                                               float* __restrict__ out)
{
  const int bid = blockIdx.x;
  const int bb = bid & 31, rg = bid >> 5;     // rg 0..7: 32-row group
  const int t = threadIdx.x, w = t >> 6, l = t & 63, q = l >> 4, ln = l & 15;
  __shared__ u16 As[16384];     // oc tile [koct(64)][row(32)][8]
  __shared__ u16 Ms[16384];     // mh tile, same layout (k = combine out col)
  __shared__ float rsL[16][32];
  const int abase = (bb*256 + rg*32)*512;
  #pragma unroll
  for (int c=0;c<2;c++) {
    int chunk = t + 1024*c;
    gload16(&oc[abase + (chunk & 31)*512 + (chunk >> 5)*8], &As[chunk*8]);
  }
  __syncthreads();
  // ---- phase 1: combine. wave w covers cols w*32..w*32+31 ----
  f32x4 acc1[2][2];
  #pragma unroll
  for (int i=0;i<2;i++)
    #pragma unroll
    for (int ct=0;ct<2;ct++)
      #pragma unroll
      for (int r=0;r<4;r++) acc1[i][ct][r] = 0.f;
  for (int kc=0;kc<16;kc++) {
    bf16x8 af[2];
    #pragma unroll
    for (int i=0;i<2;i++) af[i] = *(bf16x8*)&As[((kc*4 + q)*32 + i*16 + ln)*8];
    #pragma unroll
    for (int ct=0;ct<2;ct++) {
      int col = w*32 + ct*16 + ln;
      bf16x8 bfr = *(const bf16x8*)&WtC[col*512 + kc*32 + q*8];
      #pragma unroll
      for (int i=0;i<2;i++) acc1[i][ct] = MFMA16(af[i], bfr, acc1[i][ct]);
    }
  }
  #pragma unroll
  for (int ct=0;ct<2;ct++) {
    int gn = w*32 + ct*16 + ln;
    float bv = bias[gn];
    #pragma unroll
    for (int i=0;i<2;i++)
      #pragma unroll
      for (int r=0;r<4;r++)
        Ms[(gn >> 3)*256 + (i*16 + q*4 + r)*8 + (gn & 7)] = f2bf(acc1[i][ct][r] + bv);
  }
  __syncthreads();
  // ---- phase 2: pointer logits + softmax. wave w covers cols w*64.. ----
  float rloc[2][4] = {{0.f,0.f,0.f,0.f},{0.f,0.f,0.f,0.f}};
  const int nbase = bb*524288;
  f32x4 acc[2][4];
  #pragma unroll
  for (int i=0;i<2;i++)
    #pragma unroll
    for (int ct=0;ct<4;ct++)
      #pragma unroll
      for (int r=0;r<4;r++) acc[i][ct][r] = 0.f;
  for (int kc=0;kc<16;kc++) {
    bf16x8 af[2];
    #pragma unroll
    for (int i=0;i<2;i++) af[i] = *(bf16x8*)&Ms[((kc*4 + q)*32 + i*16 + ln)*8];
    #pragma unroll
    for (int ct=0;ct<4;ct++) {
      int col = w*64 + ct*16 + ln;
      bf16x8 bfr = *(const bf16x8*)&nodesb[nbase + col*512 + kc*32 + q*8];
      #pragma unroll
      for (int i=0;i<2;i++) acc[i][ct] = MFMA16(af[i], bfr, acc[i][ct]);
    }
  }
  const float c2 = 0.08838834764831843f;   // 2/sqrt(512)
  const int prow_base = bb*256 + rg*32;
  #pragma unroll
  for (int i=0;i<2;i++) {
    #pragma unroll
    for (int ct=0;ct<4;ct++) {
      int col0 = w*64 + ct*16 + ln;
      u16x4 mv = *(const u16x4*)&maskP[((bb*16 + rg*2 + i)*1024 + col0)*16 + q*4];
      #pragma unroll
      for (int r=0;r<4;r++) {
        float x = acc[i][ct][r] * c2;
        x = fminf(fmaxf(x, -30.f), 30.f);
        float e2 = __expf(x);
        float lg = 10.f*(e2 - 1.f)*__builtin_amdgcn_rcpf(e2 + 1.f) + bf2f(mv[r]);
        float e = __expf(lg);
        rloc[i][r] += e;
        acc[i][ct][r] = e;
      }
    }
  }
  #pragma unroll
  for (int i=0;i<2;i++)
    #pragma unroll
    for (int r=0;r<4;r++) {
      float v = rloc[i][r];
      v += __shfl_xor(v,1); v += __shfl_xor(v,2); v += __shfl_xor(v,4); v += __shfl_xor(v,8);
      rloc[i][r] = v;
    }
  if (ln == 0) {
    #pragma unroll
    for (int i=0;i<2;i++)
      #pragma unroll
      for (int r=0;r<4;r++) rsL[w][i*16 + q*4 + r] = rloc[i][r];
  }
  __syncthreads();
  float inv[2][4];
  #pragma unroll
  for (int i=0;i<2;i++)
    #pragma unroll
    for (int r=0;r<4;r++) {
      float tot = 0.f;
      #pragma unroll
      for (int ww=0;ww<16;ww++) tot += rsL[ww][i*16 + q*4 + r];
      inv[i][r] = __builtin_amdgcn_rcpf(tot);
    }
  #pragma unroll
  for (int i=0;i<2;i++)
    #pragma unroll
    for (int ct=0;ct<4;ct++) {
      int col0 = w*64 + ct*16 + ln;
      #pragma unroll
      for (int r=0;r<4;r++)
        out[(prow_base + i*16 + q*4 + r)*1024 + col0] = acc[i][ct][r]*inv[i][r];
    }
}

extern "C" void kernel_launch(void* const* d_in, const int* in_sizes, int n_in,
                              void* d_out, int out_size, void* d_ws, size_t ws_size,
                              hipStream_t stream)
{
  (void)in_sizes; (void)n_in; (void)out_size; (void)ws_size;
  const float* nodes = (const float*)d_in[0];
  const float* q1    = (const float*)d_in[1];
  const float* lastn = (const float*)d_in[2];
  const float* mask  = (const float*)d_in[3];
  const float* Wqf   = (const float*)d_in[4];
  const float* Wql   = (const float*)d_in[5];
  const float* Wk    = (const float*)d_in[6];
  const float* Wv    = (const float*)d_in[7];
  const float* Wc    = (const float*)d_in[8];
  const float* bias  = (const float*)d_in[9];
  float* out = (float*)d_out;

  char* p = (char*)d_ws;
  u16* nodesb = (u16*)p; p += 33554432;   // [32][1024][512] bf16
  u16* qlb    = (u16*)p; p += 16777216;   // [8192][1024]  = [q1 | last]
  u16* WtKV   = (u16*)p; p += 1048576;    // [1024][512]
  u16* WtQ2   = (u16*)p; p += 1048576;    // [512][1024]   = [Wqf | Wql]
  u16* WtC    = (u16*)p; p += 524288;
  u16* Kt     = (u16*)p; p += 33554432;   // K [32][16][1024][32]
  u16* Vt     = (u16*)p; p += 33554432;   // V^T [32][16][32][1024]
  u16* Qh     = (u16*)p; p += 8388608;    // Q(scaled) [32][16][256][32]
  u16* maskP  = (u16*)p; p += 16777216;   // [32][16][1024][16] bf16
  u16* oc  = qlb;   // dead after kvq

  prep<<<4096, 256, 0, stream>>>(nodes, q1, lastn, mask, Wqf, Wql, Wk, Wv, Wc,
                                 nodesb, qlb, WtKV, WtQ2, WtC, maskP);
  kvq<<<2304, 512, 0, stream>>>(nodesb, WtKV, qlb, WtQ2, Kt, Vt, Qh);
  attn<<<2048, 256, 0, stream>>>(Qh, Kt, Vt, maskP, oc);
  cmbfin<<<256, 1024, 0, stream>>>(oc, WtC, bias, nodesb, maskP, out);
}

// Round 3
// 373.221 us; speedup vs baseline: 1.2201x; 1.0263x over previous
//
#include <hip/hip_runtime.h>
#include <math.h>

typedef unsigned short u16;
typedef __attribute__((ext_vector_type(8))) short bf16x8;
typedef __attribute__((ext_vector_type(4))) float f32x4;
typedef __attribute__((ext_vector_type(4))) int i32x4;
typedef __attribute__((ext_vector_type(4))) short s16x4;
typedef __attribute__((ext_vector_type(4))) unsigned short u16x4;

#define MFMA16(a,b,c) __builtin_amdgcn_mfma_f32_16x16x32_bf16((a),(b),(c),0,0,0)

__device__ __forceinline__ u16 f2bf(float x){
  unsigned int u = __float_as_uint(x);
  u += 0x7fffu + ((u >> 16) & 1u);   // RNE
  return (u16)(u >> 16);
}
__device__ __forceinline__ float bf2f(u16 x){
  return __uint_as_float(((unsigned)x) << 16);
}
// async global->LDS, 16B per lane. LDS image must be lane-linear.
__device__ __forceinline__ void gload16(const void* g, void* l){
  __builtin_amdgcn_global_load_lds((const __attribute__((address_space(1))) void*)g,
                                   (__attribute__((address_space(3))) void*)l, 16, 0, 0);
}

// ---------------------------------------------------------------------------
// prep: fp32->bf16 + weight transposes + maskP packing.
// qlb[8192][1024] = [q1 | last]  (concat along K so Q-proj is one K=1024 GEMM)
// WtQ2[512][1024] = [Wqf | Wql]  (B^T layout, concat along K)
// maskP[b][rt(16)][col(1024)][p(16)] bf16, p = row-in-16 (MFMA C-layout order).
// grid = 4096 x 256.
// ---------------------------------------------------------------------------
__global__ __launch_bounds__(256) void prep(
    const float* __restrict__ nodes, const float* __restrict__ q1, const float* __restrict__ lastn,
    const float* __restrict__ mask,
    const float* __restrict__ Wqf, const float* __restrict__ Wql, const float* __restrict__ Wk,
    const float* __restrict__ Wv, const float* __restrict__ Wc,
    u16* __restrict__ nodesb, u16* __restrict__ qlb,
    u16* __restrict__ WtKV, u16* __restrict__ WtQ2, u16* __restrict__ WtC,
    u16* __restrict__ maskP)
{
  const int tid = blockIdx.x * 256 + threadIdx.x;
  const int NT = 1048576;
  for (int i = tid; i < 4194304; i += NT) {
    float4 v = ((const float4*)nodes)[i];
    u16x4 o; o[0]=f2bf(v.x); o[1]=f2bf(v.y); o[2]=f2bf(v.z); o[3]=f2bf(v.w);
    *(u16x4*)&nodesb[i*4] = o;
  }
  {
    const int m = tid >> 7, k4 = (tid & 127)*4;
    float4 v = ((const float4*)q1)[tid];
    u16x4 o; o[0]=f2bf(v.x); o[1]=f2bf(v.y); o[2]=f2bf(v.z); o[3]=f2bf(v.w);
    *(u16x4*)&qlb[m*1024 + k4] = o;
    v = ((const float4*)lastn)[tid];
    o[0]=f2bf(v.x); o[1]=f2bf(v.y); o[2]=f2bf(v.z); o[3]=f2bf(v.w);
    *(u16x4*)&qlb[m*1024 + 512 + k4] = o;
  }
  if (tid < 262144) {
    int n = tid >> 9, k = tid & 511;
    WtQ2[n*1024 + k]       = f2bf(Wqf[k*512 + n]);
    WtQ2[n*1024 + 512 + k] = f2bf(Wql[k*512 + n]);
    WtC[tid]  = f2bf(Wc[k*512 + n]);
  }
  if (tid < 524288) {
    int n = tid >> 9, k = tid & 511;
    WtKV[tid] = f2bf(n < 512 ? Wk[k*512 + n] : Wv[k*512 + (n-512)]);
  }
  if (tid < 524288) {  // maskP: tid = (b*16 + rt)*1024 + c
    int brt = tid >> 10, c = tid & 1023;
    const float* mp = mask + (brt*16)*1024 + c;
    u16 vals[16];
    #pragma unroll
    for (int p=0;p<16;p++) vals[p] = f2bf(mp[p*1024]);
    *(i32x4*)&maskP[tid*16]     = *(i32x4*)&vals[0];
    *(i32x4*)&maskP[tid*16 + 8] = *(i32x4*)&vals[8];
  }
}

// ---------------------------------------------------------------------------
// kvq: ONE code path, 8 waves (512 thr), 128(M)x256(N) tile, BK=32 dbuf.
//   bids 0..127    : Q tiles  (A=qlb [8192][1024], B=WtQ2 [512][1024], 32 kc)
//   bids 128..1151 : KV tiles (A=nodesb [32768][512], B=WtKV [1024][512], 16 kc)
// Waves: 2(M) x 4(N), per-wave 64x64 output -> acc[4][4] (AGPRs).
// Per wave-step: 8 ds_read_b128 -> 16 MFMA (2:1). launch_bounds(512,2)
// leaves the allocator ~256 regs so fragment reads stay pipelined
// (R2's forced 64-reg cap serialized every wave; occupancy didn't help).
// LDS 49152 B -> 2-3 blocks/CU. Epilogue: four 64-col passes through a
// 64x140 transpose buffer (reuses staging LDS).
// ---------------------------------------------------------------------------
__global__ __launch_bounds__(512, 2) void kvq(
    const u16* __restrict__ Akv, const u16* __restrict__ Bkv,
    const u16* __restrict__ Aq,  const u16* __restrict__ Bq,
    u16* __restrict__ Kout, u16* __restrict__ Vout, u16* __restrict__ Qout)
{
  __shared__ u16 smem[24576];   // 49152 B: 2 x (A 8KB + B 16KB)
  const int t = threadIdx.x, w = t >> 6, l = t & 63, q = l >> 4, ln = l & 15;
  const int wr = w >> 2, wc = w & 3;
  const int wm = wr * 64, wn = wc * 64;

  const bool isq = blockIdx.x < 128;
  int mb, nb, ksteps, kstr;
  const u16 *Ab, *Bb;
  if (isq) {
    const int bid = blockIdx.x;
    mb = bid >> 1; nb = bid & 1;
    ksteps = 32; kstr = 1024; Ab = Aq; Bb = Bq;
  } else {
    const int bid = blockIdx.x - 128;
    mb = (bid >> 5)*8 + (bid & 7);        // XCD swizzle (same-A blocks share XCD)
    nb = (bid >> 3) & 3;
    ksteps = 16; kstr = 512; Ab = Akv; Bb = Bkv;
  }
  const int m0 = mb*128, n0 = nb*256;

  f32x4 acc[4][4];
  #pragma unroll
  for (int i=0;i<4;i++)
    #pragma unroll
    for (int j=0;j<4;j++)
      #pragma unroll
      for (int r=0;r<4;r++) acc[i][j][r] = 0.f;

  // staging: A 8KB = 512 lanes x 16B; B 16KB = 512 lanes x 2 x 16B
  const u16* Aaddr = Ab + (m0 + (t & 127))*kstr + (t >> 7)*8;
  const u16* Baddr = Bb + (n0 + (t & 255))*kstr + (t >> 8)*8;

  #define STAGE(kc_, b_) { \
    u16* s = smem + (b_)*12288; \
    gload16(Aaddr + (kc_)*32,      &s[t*8]); \
    gload16(Baddr + (kc_)*32,      &s[4096 + t*8]); \
    gload16(Baddr + 16 + (kc_)*32, &s[4096 + (t+512)*8]); }

  STAGE(0, 0);
  for (int kc = 0; kc < ksteps; kc++) {
    __syncthreads();
    if (kc + 1 < ksteps) STAGE(kc+1, (kc+1)&1);
    const u16* sa = smem + (kc&1)*12288;
    const u16* sb = sa + 4096;
    bf16x8 af[4], bfr[4];
    #pragma unroll
    for (int i=0;i<4;i++) af[i]  = *(bf16x8*)&sa[(q*128 + wm + i*16 + ln)*8];
    #pragma unroll
    for (int j=0;j<4;j++) bfr[j] = *(bf16x8*)&sb[(q*256 + wn + j*16 + ln)*8];
    #pragma unroll
    for (int i=0;i<4;i++)
      #pragma unroll
      for (int j=0;j<4;j++)
        acc[i][j] = MFMA16(af[i], bfr[j], acc[i][j]);
  }
  #undef STAGE

  // ---- epilogue: four 64-col passes via 64x140 buffer (17920 B) ----
  const float scale = isq ? 0.17677669529663687f : 1.0f;
  const int bb_ = mb >> 3, mloc = (mb & 7)*128;   // kv decode
  const int bbq = mb >> 1, pm0 = (mb & 1)*128;    // q  decode
  for (int h = 0; h < 4; ++h) {
    __syncthreads();
    if (wc == h) {
      #pragma unroll
      for (int i=0;i<4;i++)
        #pragma unroll
        for (int j=0;j<4;j++) {
          s16x4 o;
          #pragma unroll
          for (int r=0;r<4;r++) o[r] = (short)f2bf(acc[i][j][r]*scale);
          *(s16x4*)&smem[(j*16 + ln)*140 + wm + i*16 + q*4] = o;
        }
    }
    __syncthreads();
    #pragma unroll
    for (int hc=0; hc<2; ++hc) {
      if (isq) {
        const int head = nb*8 + h*2 + hc;
        const int m_ = t >> 2, d0 = (t & 3)*8;
        u16 v[8];
        #pragma unroll
        for (int dd=0;dd<8;dd++) v[dd] = smem[(hc*32 + d0 + dd)*140 + m_];
        *(i32x4*)&Qout[((bbq*16 + head)*256 + pm0 + m_)*32 + d0] = *(i32x4*)&v[0];
      } else if (nb < 2) {
        const int head = nb*8 + h*2 + hc;
        const int m_ = t >> 2, d0 = (t & 3)*8;
        u16 v[8];
        #pragma unroll
        for (int dd=0;dd<8;dd++) v[dd] = smem[(hc*32 + d0 + dd)*140 + m_];
        *(i32x4*)&Kout[((bb_*16 + head)*1024 + mloc + m_)*32 + d0] = *(i32x4*)&v[0];
      } else {
        const int vh = (nb-2)*8 + h*2 + hc;
        const int d = t >> 4, mo = (t & 15)*8;
        *(i32x4*)&Vout[((bb_*16 + vh)*32 + d)*1024 + mloc + mo]
            = *(i32x4*)&smem[(hc*32 + d)*140 + mo];
      }
    }
  }
}

// ---------------------------------------------------------------------------
// Fused attention per (b, h, pomo64). grid = 2048, 4 waves.
// XCD swizzle: bid = bhhi*32 + pt*8 + bhlo -> 4 pt-blocks sharing K/V on one
// XCD within a 32-bid window.
// ---------------------------------------------------------------------------
__global__ __launch_bounds__(256) void attn(const u16* __restrict__ Qg, const u16* __restrict__ Kg,
                                            const u16* __restrict__ Vtg, const u16* __restrict__ maskP,
                                            u16* __restrict__ Og)
{
  const int bid = blockIdx.x;
  const int bh = (bid >> 5)*8 + (bid & 7);       // 0..511
  const int pt = (bid >> 3) & 3;
  const int h = bh & 15, bb = bh >> 4;
  const int t = threadIdx.x, w = t >> 6, l = t & 63, q = l >> 4, ln = l & 15;
  __shared__ u16 Qs[2048];     // [qk(4)][row(64)][8]
  __shared__ u16 Ks[4096];     // [qk(4)][m(128)][8]
  __shared__ u16 Vs[4096];     // [moct(16)][d(32)][8]
  __shared__ u16 Ps[4*640];    // per wave [16][40]
  u16* Pw = &Ps[w*640];
  const int qbase = ((bb*16 + h)*256 + pt*64)*32;
  gload16(&Qg[qbase + (t & 63)*32 + (t >> 6)*8], &Qs[t*8]);
  const int kbase = (bb*16 + h)*1024*32;
  const int vbase = (bb*16 + h)*32*1024;
  float rs[4] = {0.f,0.f,0.f,0.f};
  f32x4 oacc[2];
  #pragma unroll
  for (int dt=0;dt<2;dt++)
    #pragma unroll
    for (int r=0;r<4;r++) oacc[dt][r] = 0.f;
  __syncthreads();
  const bf16x8 aq = *(bf16x8*)&Qs[(q*64 + w*16 + ln)*8];
  const u16* mrow = maskP + (bb*16 + pt*4 + w)*16384 + q*4;
  for (int mc = 0; mc < 8; mc++) {
    __syncthreads();
    gload16(&Kg[kbase + (mc*128 + (t & 127))*32 + (t >> 7)*8],       &Ks[t*8]);
    gload16(&Kg[kbase + (mc*128 + (t & 127))*32 + ((t >> 7)+2)*8],   &Ks[(t+256)*8]);
    gload16(&Vtg[vbase + (t & 31)*1024 + mc*128 + (t >> 5)*8],       &Vs[t*8]);
    gload16(&Vtg[vbase + (t & 31)*1024 + mc*128 + ((t >> 5)+8)*8],   &Vs[(t+256)*8]);
    u16x4 mq[8];
    #pragma unroll
    for (int j2=0;j2<8;j2++)
      mq[j2] = *(const u16x4*)&mrow[(mc*128 + j2*16 + ln)*16];
    __syncthreads();
    #pragma unroll
    for (int ch=0; ch<4; ch++) {
      bf16x8 bk0 = *(bf16x8*)&Ks[(q*128 + (ch*2+0)*16 + ln)*8];
      bf16x8 bk1 = *(bf16x8*)&Ks[(q*128 + (ch*2+1)*16 + ln)*8];
      f32x4 zz = {0.f,0.f,0.f,0.f};
      f32x4 s0 = MFMA16(aq, bk0, zz);
      f32x4 s1 = MFMA16(aq, bk1, zz);
      #pragma unroll
      for (int r=0;r<4;r++) {
        float e0 = __expf(s0[r] + bf2f(mq[ch*2+0][r]));
        float e1 = __expf(s1[r] + bf2f(mq[ch*2+1][r]));
        rs[r] += e0 + e1;
        Pw[(q*4+r)*40 + ln]      = f2bf(e0);
        Pw[(q*4+r)*40 + 16 + ln] = f2bf(e1);
      }
      bf16x8 ap  = *(bf16x8*)&Pw[ln*40 + q*8];
      bf16x8 bv0 = *(bf16x8*)&Vs[((ch*4+q)*32 + ln)*8];
      bf16x8 bv1 = *(bf16x8*)&Vs[((ch*4+q)*32 + 16 + ln)*8];
      oacc[0] = MFMA16(ap, bv0, oacc[0]);
      oacc[1] = MFMA16(ap, bv1, oacc[1]);
    }
  }
  #pragma unroll
  for (int r=0;r<4;r++) {
    float v = rs[r];
    v += __shfl_xor(v,1); v += __shfl_xor(v,2); v += __shfl_xor(v,4); v += __shfl_xor(v,8);
    rs[r] = __builtin_amdgcn_rcpf(v);
  }
  const int orow = bb*256 + pt*64 + w*16 + q*4;
  #pragma unroll
  for (int dt=0;dt<2;dt++)
    #pragma unroll
    for (int r=0;r<4;r++)
      Og[(orow + r)*512 + h*32 + dt*16 + ln] = f2bf(oacc[dt][r]*rs[r]);
}

// ---------------------------------------------------------------------------
// cmbfin: fused combine-GEMM + pointer-GEMM + tanh-softmax.
// 1024 threads (16 waves), 32 rows x 1024 cols per block, grid = 256
// (1 block/CU). XCD swizzle: bid = rg*32 + bb -> all 8 row-groups of batch b
// on one XCD (nodesb[b] = 1 MB stays in that XCD's L2; 4 b's = 4 MB = L2).
// ---------------------------------------------------------------------------
__global__ __launch_bounds__(1024) void cmbfin(const u16* __restrict__ oc, const u16* __restrict__ WtC,
                                               const float* __restrict__ bias,
                                               const u16* __restrict__ nodesb, const u16* __restrict__ maskP,
                                               float* __restrict__ out)
{
  const int bid = blockIdx.x;
  const int bb = bid & 31, rg = bid >> 5;     // rg 0..7: 32-row group
  const int t = threadIdx.x, w = t >> 6, l = t & 63, q = l >> 4, ln = l & 15;
  __shared__ u16 As[16384];     // oc tile [koct(64)][row(32)][8]
  __shared__ u16 Ms[16384];     // mh tile, same layout (k = combine out col)
  __shared__ float rsL[16][32];
  const int abase = (bb*256 + rg*32)*512;
  #pragma unroll
  for (int c=0;c<2;c++) {
    int chunk = t + 1024*c;
    gload16(&oc[abase + (chunk & 31)*512 + (chunk >> 5)*8], &As[chunk*8]);
  }
  __syncthreads();
  // ---- phase 1: combine. wave w covers cols w*32..w*32+31 ----
  f32x4 acc1[2][2];
  #pragma unroll
  for (int i=0;i<2;i++)
    #pragma unroll
    for (int ct=0;ct<2;ct++)
      #pragma unroll
      for (int r=0;r<4;r++) acc1[i][ct][r] = 0.f;
  for (int kc=0;kc<16;kc++) {
    bf16x8 af[2];
    #pragma unroll
    for (int i=0;i<2;i++) af[i] = *(bf16x8*)&As[((kc*4 + q)*32 + i*16 + ln)*8];
    #pragma unroll
    for (int ct=0;ct<2;ct++) {
      int col = w*32 + ct*16 + ln;
      bf16x8 bfr = *(const bf16x8*)&WtC[col*512 + kc*32 + q*8];
      #pragma unroll
      for (int i=0;i<2;i++) acc1[i][ct] = MFMA16(af[i], bfr, acc1[i][ct]);
    }
  }
  #pragma unroll
  for (int ct=0;ct<2;ct++) {
    int gn = w*32 + ct*16 + ln;
    float bv = bias[gn];
    #pragma unroll
    for (int i=0;i<2;i++)
      #pragma unroll
      for (int r=0;r<4;r++)
        Ms[(gn >> 3)*256 + (i*16 + q*4 + r)*8 + (gn & 7)] = f2bf(acc1[i][ct][r] + bv);
  }
  __syncthreads();
  // ---- phase 2: pointer logits + softmax. wave w covers cols w*64.. ----
  float rloc[2][4] = {{0.f,0.f,0.f,0.f},{0.f,0.f,0.f,0.f}};
  const int nbase = bb*524288;
  f32x4 acc[2][4];
  #pragma unroll
  for (int i=0;i<2;i++)
    #pragma unroll
    for (int ct=0;ct<4;ct++)
      #pragma unroll
      for (int r=0;r<4;r++) acc[i][ct][r] = 0.f;
  for (int kc=0;kc<16;kc++) {
    bf16x8 af[2];
    #pragma unroll
    for (int i=0;i<2;i++) af[i] = *(bf16x8*)&Ms[((kc*4 + q)*32 + i*16 + ln)*8];
    #pragma unroll
    for (int ct=0;ct<4;ct++) {
      int col = w*64 + ct*16 + ln;
      bf16x8 bfr = *(const bf16x8*)&nodesb[nbase + col*512 + kc*32 + q*8];
      #pragma unroll
      for (int i=0;i<2;i++) acc[i][ct] = MFMA16(af[i], bfr, acc[i][ct]);
    }
  }
  const float c2 = 0.08838834764831843f;   // 2/sqrt(512)
  const int prow_base = bb*256 + rg*32;
  #pragma unroll
  for (int i=0;i<2;i++) {
    #pragma unroll
    for (int ct=0;ct<4;ct++) {
      int col0 = w*64 + ct*16 + ln;
      u16x4 mv = *(const u16x4*)&maskP[((bb*16 + rg*2 + i)*1024 + col0)*16 + q*4];
      #pragma unroll
      for (int r=0;r<4;r++) {
        float x = acc[i][ct][r] * c2;
        x = fminf(fmaxf(x, -30.f), 30.f);
        float e2 = __expf(x);
        float lg = 10.f*(e2 - 1.f)*__builtin_amdgcn_rcpf(e2 + 1.f) + bf2f(mv[r]);
        float e = __expf(lg);
        rloc[i][r] += e;
        acc[i][ct][r] = e;
      }
    }
  }
  #pragma unroll
  for (int i=0;i<2;i++)
    #pragma unroll
    for (int r=0;r<4;r++) {
      float v = rloc[i][r];
      v += __shfl_xor(v,1); v += __shfl_xor(v,2); v += __shfl_xor(v,4); v += __shfl_xor(v,8);
      rloc[i][r] = v;
    }
  if (ln == 0) {
    #pragma unroll
    for (int i=0;i<2;i++)
      #pragma unroll
      for (int r=0;r<4;r++) rsL[w][i*16 + q*4 + r] = rloc[i][r];
  }
  __syncthreads();
  float inv[2][4];
  #pragma unroll
  for (int i=0;i<2;i++)
    #pragma unroll
    for (int r=0;r<4;r++) {
      float tot = 0.f;
      #pragma unroll
      for (int ww=0;ww<16;ww++) tot += rsL[ww][i*16 + q*4 + r];
      inv[i][r] = __builtin_amdgcn_rcpf(tot);
    }
  #pragma unroll
  for (int i=0;i<2;i++)
    #pragma unroll
    for (int ct=0;ct<4;ct++) {
      int col0 = w*64 + ct*16 + ln;
      #pragma unroll
      for (int r=0;r<4;r++)
        out[(prow_base + i*16 + q*4 + r)*1024 + col0] = acc[i][ct][r]*inv[i][r];
    }
}

extern "C" void kernel_launch(void* const* d_in, const int* in_sizes, int n_in,
                              void* d_out, int out_size, void* d_ws, size_t ws_size,
                              hipStream_t stream)
{
  (void)in_sizes; (void)n_in; (void)out_size; (void)ws_size;
  const float* nodes = (const float*)d_in[0];
  const float* q1    = (const float*)d_in[1];
  const float* lastn = (const float*)d_in[2];
  const float* mask  = (const float*)d_in[3];
  const float* Wqf   = (const float*)d_in[4];
  const float* Wql   = (const float*)d_in[5];
  const float* Wk    = (const float*)d_in[6];
  const float* Wv    = (const float*)d_in[7];
  const float* Wc    = (const float*)d_in[8];
  const float* bias  = (const float*)d_in[9];
  float* out = (float*)d_out;

  char* p = (char*)d_ws;
  u16* nodesb = (u16*)p; p += 33554432;   // [32][1024][512] bf16
  u16* qlb    = (u16*)p; p += 16777216;   // [8192][1024]  = [q1 | last]
  u16* WtKV   = (u16*)p; p += 1048576;    // [1024][512]
  u16* WtQ2   = (u16*)p; p += 1048576;    // [512][1024]   = [Wqf | Wql]
  u16* WtC    = (u16*)p; p += 524288;
  u16* Kt     = (u16*)p; p += 33554432;   // K [32][16][1024][32]
  u16* Vt     = (u16*)p; p += 33554432;   // V^T [32][16][32][1024]
  u16* Qh     = (u16*)p; p += 8388608;    // Q(scaled) [32][16][256][32]
  u16* maskP  = (u16*)p; p += 16777216;   // [32][16][1024][16] bf16
  u16* oc  = qlb;   // dead after kvq

  prep<<<4096, 256, 0, stream>>>(nodes, q1, lastn, mask, Wqf, Wql, Wk, Wv, Wc,
                                 nodesb, qlb, WtKV, WtQ2, WtC, maskP);
  kvq<<<1152, 512, 0, stream>>>(nodesb, WtKV, qlb, WtQ2, Kt, Vt, Qh);
  attn<<<2048, 256, 0, stream>>>(Qh, Kt, Vt, maskP, oc);
  cmbfin<<<256, 1024, 0, stream>>>(oc, WtC, bias, nodesb, maskP, out);
}